// Round 8
// baseline (64.625 us; speedup 1.0000x reference)
//
#include <hip/hip_runtime.h>
#include <math.h>

// MaxofErosions2D, packed-f16 + LDS-tiled, 8 px/thread (1 row x 8 cols).
// out[b,h,w,f] = max_c min_{dy,dx} ( x[b,h+dy-2,w+dx-2,c] - kern[4-dy,4-dx,c,f] )
// x: (32,256,256,3) f32, kern: (5,5,3,8) f32, out: (32,256,256,8) f32.
//
// Block = 8 h-rows x 256 w (2048 px), thread = 8 consecutive w-pixels.
// vs R7 (4 px/thread): klds reads 18.8 -> 9.4 per px, x reads 7.5 -> 5.6 per px,
// staging/epilogue amortized 2x. dy loop kept ROLLED (#pragma unroll 1) so the
// hot body (~8 KB) stays I-cache-resident (R7's full unroll was ~20+ KB).
// ero[8][3][4] h2 in regs (~96 VGPR) -- all indices compile-time constant.

typedef _Float16 h2 __attribute__((ext_vector_type(2)));

static __device__ __forceinline__ h2 cvt_pk(float a, float b) {
    return __builtin_bit_cast(h2, __builtin_amdgcn_cvt_pkrtz(a, b));
}
static __device__ __forceinline__ h2 u2h(unsigned u) {
    return __builtin_bit_cast(h2, u);
}

#define Hq 256
#define RSTR 792            // h2 per tile row = 264 cols * 3 ch
#define TROWS 12            // 8 output rows + 4 halo
#define TILE_H2 (TROWS * RSTR)   // 9504 h2 = 38016 B
#define INF2 0x7C007C00u

__global__ __launch_bounds__(256) void maxero8(
    const float* __restrict__ x,
    const float* __restrict__ kern,
    float* __restrict__ out)
{
    __shared__ h2 xlds[TILE_H2];
    __shared__ h2 klds[25 * 12];

    const int tid = threadIdx.x;
    const int bI  = blockIdx.x;        // 1024 blocks
    const int b   = bI >> 5;           // image
    const int h0  = (bI & 31) << 3;    // block's first output row (8 rows/block)

    // ---- stage kernel: pre-flipped, filter-pair packed (300 > 256: strided!)
    for (int i = tid; i < 300; i += 256) {
        int tap = i / 12;
        int rem = i - tap * 12;
        int c = rem >> 2, fp = rem & 3;
        int dy = tap / 5, dx = tap - dy * 5;
        const float* kp = kern + (((4 - dy) * 5 + (4 - dx)) * 24) + c * 8 + fp * 2;
        klds[i] = cvt_pk(kp[0], kp[1]);
    }

    // ---- stage x tile: 12 rows x 256 cols x 3 ch = 2304 float4 chunks (9/thread)
    const float* xb = x + (size_t)b * (Hq * 256 * 3);
    #pragma unroll
    for (int k = 0; k < 9; ++k) {
        int chunk = tid + k * 256;            // 0..2303
        int rr    = chunk / 192;              // 192 float4 per row
        int off   = (chunk - rr * 192) * 4;   // float offset in row
        int r     = h0 - 2 + rr;
        bool rv   = (unsigned)r < (unsigned)Hq;
        int rc    = min(max(r, 0), Hq - 1);
        const float4 v = *reinterpret_cast<const float4*>(xb + rc * 768 + off);
        h2* d = &xlds[rr * RSTR + 18 + off];
        d[0] = rv ? cvt_pk(v.x, v.x) : u2h(INF2);
        d[1] = rv ? cvt_pk(v.y, v.y) : u2h(INF2);
        d[2] = rv ? cvt_pk(v.z, v.z) : u2h(INF2);
        d[3] = rv ? cvt_pk(v.w, v.w) : u2h(INF2);
    }
    // halo fill: 12 rows x (18 left + 6 right) = 288 entries (288 > 256: strided!)
    for (int i = tid; i < 288; i += 256) {
        int rr = i / 24, p = i - rr * 24;
        xlds[rr * RSTR + (p < 18 ? p : 768 + p)] = u2h(INF2);
    }
    __syncthreads();

    const int hrow = tid >> 5;            // 0..7
    const int w0   = (tid & 31) << 3;     // 0..248, 8 pixels per thread

    h2 ero[8][3][4];
    #pragma unroll
    for (int p = 0; p < 8; ++p)
        #pragma unroll
        for (int c = 0; c < 3; ++c)
            #pragma unroll
            for (int fp = 0; fp < 4; ++fp)
                ero[p][c][fp] = u2h(INF2);

    #pragma unroll 1   // keep rolled: body ~8 KB, I-cache resident
    for (int dy = 0; dy < 5; ++dy) {
        // 12 columns (w0-2 .. w0+9) x 3 ch = 36 contiguous h2, 16B-aligned:
        // h2 base = row*RSTR + (6 + w0-2)*3 = row*RSTR + 12 + 3*w0 (byte 48+96m)
        const uint4* rp = reinterpret_cast<const uint4*>(
            &xlds[(hrow + dy) * RSTR + 12 + 3 * w0]);
        unsigned xq[36];
        #pragma unroll
        for (int q = 0; q < 9; ++q) {
            uint4 t = rp[q];
            xq[q * 4 + 0] = t.x; xq[q * 4 + 1] = t.y;
            xq[q * 4 + 2] = t.z; xq[q * 4 + 3] = t.w;
        }
        const uint4* kb = reinterpret_cast<const uint4*>(&klds[dy * 60]);
        #pragma unroll
        for (int dx = 0; dx < 5; ++dx) {
            uint4 k0 = kb[dx * 3 + 0], k1 = kb[dx * 3 + 1], k2 = kb[dx * 3 + 2];
            const unsigned kf[12] = { k0.x, k0.y, k0.z, k0.w,
                                      k1.x, k1.y, k1.z, k1.w,
                                      k2.x, k2.y, k2.z, k2.w };
            #pragma unroll
            for (int p = 0; p < 8; ++p)
                #pragma unroll
                for (int c = 0; c < 3; ++c)
                    #pragma unroll
                    for (int fp = 0; fp < 4; ++fp) {
                        h2 cand = u2h(xq[(p + dx) * 3 + c]) - u2h(kf[c * 4 + fp]);
                        ero[p][c][fp] = __builtin_elementwise_min(ero[p][c][fp], cand);
                    }
        }
    }

    // ---- epilogue: channel max, f32 output, 2x float4 per pixel
    const size_t rowbase = (size_t)b * 65536 + (size_t)(h0 + hrow) * 256 + w0;
    #pragma unroll
    for (int p = 0; p < 8; ++p) {
        float of[8];
        #pragma unroll
        for (int fp = 0; fp < 4; ++fp) {
            h2 m = __builtin_elementwise_max(
                       __builtin_elementwise_max(ero[p][0][fp], ero[p][1][fp]),
                       ero[p][2][fp]);
            of[fp * 2 + 0] = (float)m[0];
            of[fp * 2 + 1] = (float)m[1];
        }
        float* op = out + (rowbase + p) * 8;
        reinterpret_cast<float4*>(op)[0] = make_float4(of[0], of[1], of[2], of[3]);
        reinterpret_cast<float4*>(op)[1] = make_float4(of[4], of[5], of[6], of[7]);
    }
}

extern "C" void kernel_launch(void* const* d_in, const int* in_sizes, int n_in,
                              void* d_out, int out_size, void* d_ws, size_t ws_size,
                              hipStream_t stream) {
    const float* x    = (const float*)d_in[0];
    const float* kern = (const float*)d_in[1];
    float* out        = (float*)d_out;
    maxero8<<<1024, 256, 0, stream>>>(x, kern, out);   // 32 images x 32 row-groups
}

// Round 9
// 53.971 us; speedup vs baseline: 1.1974x; 1.1974x over previous
//
#include <hip/hip_runtime.h>
#include <math.h>

// MaxofErosions2D, packed-f16, LDS tile stored as NATURAL f16 pairs (halved LDS).
// out[b,h,w,f] = max_c min_{dy,dx} ( x[b,h+dy-2,w+dx-2,c] - kern[4-dy,4-dx,c,f] )
// x: (32,256,256,3) f32, kern: (5,5,3,8) f32, out: (32,256,256,8) f32.
//
// Block = 4 h-rows x 256 w (1024 px), thread = 4 consecutive w-pixels (= R7).
// R9 change vs R7 (single variable): x tile stored as natural f16 pairs
// (2 B/elem, 12.7 KB) instead of duplicated h2 (4 B/elem, 25.3 KB).
//  -> 8 blocks/CU (wave-cap) instead of 6 (LDS-cap); grid 2048 = exact fill.
// Element splat to both halves happens at use: {s,s} -> VOP3P op_sel or v_perm.
//
// Tile row layout: f16 idx = (6+col)*3 + c, col in [-6,257], 792 f16 = 396 h2/row.
// Hot read: 12 h2 (48 B) at h2 base row*396 + 6m+6 (even -> b64-aligned).

typedef _Float16 h2 __attribute__((ext_vector_type(2)));

static __device__ __forceinline__ h2 cvt_pk(float a, float b) {
    return __builtin_bit_cast(h2, __builtin_amdgcn_cvt_pkrtz(a, b));
}
static __device__ __forceinline__ h2 u2h(unsigned u) {
    return __builtin_bit_cast(h2, u);
}

#define Hq 256
#define RSTR 396                  // h2 per tile row (264 cols * 3 f16 / 2)
#define TILE_H2 (8 * RSTR)        // 3168 h2 = 12672 B
#define INF2 0x7C007C00u          // +inf f16 pair

__global__ __launch_bounds__(256) void maxero_np(
    const float* __restrict__ x,
    const float* __restrict__ kern,
    float* __restrict__ out)
{
    __shared__ __align__(16) h2 xlds[TILE_H2];
    __shared__ __align__(16) h2 klds[25 * 12];

    const int tid = threadIdx.x;
    const int bI  = blockIdx.x;        // 2048 blocks
    const int b   = bI >> 6;           // image
    const int h0  = (bI & 63) << 2;    // block's first output row

    // ---- stage kernel: pre-flipped, filter-pair packed (300 > 256: strided!)
    for (int i = tid; i < 300; i += 256) {
        int tap = i / 12;
        int rem = i - tap * 12;
        int c = rem >> 2, fp = rem & 3;
        int dy = tap / 5, dx = tap - dy * 5;
        const float* kp = kern + (((4 - dy) * 5 + (4 - dx)) * 24) + c * 8 + fp * 2;
        klds[i] = cvt_pk(kp[0], kp[1]);
    }

    // ---- stage x tile: 8 rows x 256 cols x 3 ch, natural f16 pairs
    const float* xb = x + (size_t)b * (Hq * 256 * 3);
    #pragma unroll
    for (int k = 0; k < 6; ++k) {
        int chunk = tid + k * 256;            // 0..1535
        int rr    = chunk / 192;              // 192 float4 per row
        int off   = (chunk - rr * 192) * 4;   // float offset in row (0,4,..764)
        int r     = h0 - 2 + rr;
        bool rv   = (unsigned)r < (unsigned)Hq;
        int rc    = min(max(r, 0), Hq - 1);
        const float4 v = *reinterpret_cast<const float4*>(xb + rc * 768 + off);
        // interior f16 idx = 18 + off  -> h2 idx = 9 + off/2 (odd: two b32 writes)
        h2* d = &xlds[rr * RSTR + 9 + (off >> 1)];
        d[0] = rv ? cvt_pk(v.x, v.y) : u2h(INF2);
        d[1] = rv ? cvt_pk(v.z, v.w) : u2h(INF2);
    }
    // halo fill: 8 rows x (9 left h2 + 3 right h2) = 96 entries
    if (tid < 96) {
        int rr = tid / 12, p = tid - rr * 12;
        xlds[rr * RSTR + (p < 9 ? p : 384 + p)] = u2h(INF2);  // 384+9=393..395
    }
    __syncthreads();

    const int hrow = tid >> 6;           // 0..3
    const int w0   = (tid & 63) << 2;    // 0..252

    h2 ero[4][3][4];
    #pragma unroll
    for (int p = 0; p < 4; ++p)
        #pragma unroll
        for (int c = 0; c < 3; ++c)
            #pragma unroll
            for (int fp = 0; fp < 4; ++fp)
                ero[p][c][fp] = u2h(INF2);

    #pragma unroll
    for (int dy = 0; dy < 5; ++dy) {
        // 24 f16 (cols w0-2..w0+5, 3 ch) = 12 h2, base h2 = row*396 + 6m+6 (even)
        const uint2* rp = reinterpret_cast<const uint2*>(
            &xlds[(hrow + dy) * RSTR + 6 + ((3 * w0) >> 1)]);
        unsigned nat[12];
        #pragma unroll
        for (int q = 0; q < 6; ++q) {
            uint2 t = rp[q];
            nat[q * 2 + 0] = t.x;
            nat[q * 2 + 1] = t.y;
        }
        #pragma unroll
        for (int dx = 0; dx < 5; ++dx) {
            const uint4* kk = reinterpret_cast<const uint4*>(&klds[(dy * 5 + dx) * 12]);
            uint4 k0 = kk[0], k1 = kk[1], k2 = kk[2];   // broadcast, conflict-free
            const unsigned kf[12] = { k0.x, k0.y, k0.z, k0.w,
                                      k1.x, k1.y, k1.z, k1.w,
                                      k2.x, k2.y, k2.z, k2.w };
            #pragma unroll
            for (int p = 0; p < 4; ++p)
                #pragma unroll
                for (int c = 0; c < 3; ++c) {
                    const int e = (p + dx) * 3 + c;      // element 0..23
                    _Float16 s = u2h(nat[e >> 1])[e & 1];
                    h2 xx = { s, s };                    // op_sel fold / v_perm (CSE'd)
                    #pragma unroll
                    for (int fp = 0; fp < 4; ++fp) {
                        h2 cand = xx - u2h(kf[c * 4 + fp]);
                        ero[p][c][fp] = __builtin_elementwise_min(ero[p][c][fp], cand);
                    }
                }
        }
    }

    // ---- epilogue: channel max, f32 output, 2x float4 per pixel
    const size_t rowbase = (size_t)b * 65536 + (size_t)(h0 + hrow) * 256 + w0;
    #pragma unroll
    for (int p = 0; p < 4; ++p) {
        float of[8];
        #pragma unroll
        for (int fp = 0; fp < 4; ++fp) {
            h2 m = __builtin_elementwise_max(
                       __builtin_elementwise_max(ero[p][0][fp], ero[p][1][fp]),
                       ero[p][2][fp]);
            of[fp * 2 + 0] = (float)m[0];
            of[fp * 2 + 1] = (float)m[1];
        }
        float* op = out + (rowbase + p) * 8;
        reinterpret_cast<float4*>(op)[0] = make_float4(of[0], of[1], of[2], of[3]);
        reinterpret_cast<float4*>(op)[1] = make_float4(of[4], of[5], of[6], of[7]);
    }
}

extern "C" void kernel_launch(void* const* d_in, const int* in_sizes, int n_in,
                              void* d_out, int out_size, void* d_ws, size_t ws_size,
                              hipStream_t stream) {
    const float* x    = (const float*)d_in[0];
    const float* kern = (const float*)d_in[1];
    float* out        = (float*)d_out;
    maxero_np<<<2048, 256, 0, stream>>>(x, kern, out);  // 32 images x 64 row-groups
}